// Round 8
// baseline (291.188 us; speedup 1.0000x reference)
//
#include <hip/hip_runtime.h>
#include <hip/hip_bf16.h>
#include <math.h>

#define BSZ 8
#define LQ  1024
#define LV  13294
#define NH  8
#define HD  32
#define VM  (BSZ * LV)   // 106352 rows of value
#define MQ  (BSZ * LQ)   // 8192 query rows

typedef __attribute__((ext_vector_type(8))) short bf16x8;
typedef __attribute__((ext_vector_type(4))) float f32x4;

__device__ static inline unsigned short f2bf(float f) {
    unsigned int u = __float_as_uint(f);
    unsigned int r = (u + 0x7FFFu + ((u >> 16) & 1u)) >> 16;
    return (unsigned short)r;
}
__device__ static inline float bf2f(unsigned short s) {
    return __uint_as_float(((unsigned int)s) << 16);
}
__device__ static inline unsigned int pk2bf(float a, float b) {
    __hip_bfloat162 h = __float22bfloat162_rn(make_float2(a, b));
    return *(unsigned int*)&h;
}

// ---------------------------------------------------------------------------
// Prep kernel:
//  blocks [0,256):      vp_w [k][256] -> wTv [kc][n][kk] bf16
//  blocks [256,512):    op_w [k][256] -> wTo [kc][n][kk] bf16
//  blocks [512,768):    so_w [k][256] -> wTso [kc][n][kk] bf16
//  blocks [768,896):    aw_w [k][128] -> wTaw [kc][n][kk] bf16
//  blocks [896,2944):   query f32 -> qhi/qlo bf16 split (4 elems/thread)
// ---------------------------------------------------------------------------
__global__ __launch_bounds__(256) void prep_kernel(
    const float* __restrict__ vp_w, const float* __restrict__ op_w,
    const float* __restrict__ so_w, const float* __restrict__ aw_w,
    const float* __restrict__ query,
    unsigned short* __restrict__ wTv, unsigned short* __restrict__ wTo,
    unsigned short* __restrict__ wTso, unsigned short* __restrict__ wTaw,
    unsigned short* __restrict__ qhi, unsigned short* __restrict__ qlo)
{
    const int blk = blockIdx.x;
    const int t   = threadIdx.x;
    if (blk < 768) {
        const int n = blk & 255;
        const int k = t;
        const float* w; unsigned short* o;
        if      (blk < 256) { w = vp_w; o = wTv; }
        else if (blk < 512) { w = op_w; o = wTo; }
        else                { w = so_w; o = wTso; }
        o[(((k >> 5) * 256 + n) << 5) + (k & 31)] = f2bf(w[k * 256 + n]);
    } else if (blk < 896) {
        const int n = blk - 768;          // 0..127
        const int k = t;
        wTaw[(((k >> 5) * 128 + n) << 5) + (k & 31)] = f2bf(aw_w[k * 128 + n]);
    } else {
        const int idx = (blk - 896) * 256 + t;       // 2,097,152 float4 / 4
        const float4 f = *(const float4*)(query + (size_t)idx * 4);
        ushort4 hi, lo;
        hi.x = f2bf(f.x); lo.x = f2bf(f.x - bf2f(hi.x));
        hi.y = f2bf(f.y); lo.y = f2bf(f.y - bf2f(hi.y));
        hi.z = f2bf(f.z); lo.z = f2bf(f.z - bf2f(hi.z));
        hi.w = f2bf(f.w); lo.w = f2bf(f.w - bf2f(hi.w));
        *(ushort4*)(qhi + (size_t)idx * 4) = hi;
        *(ushort4*)(qlo + (size_t)idx * 4) = lo;
    }
}

// ---------------------------------------------------------------------------
// vproj v9: BM=32, 8 blocks/CU. A staged once (coalesced, swizzled), one
// barrier, W direct from L2 in K-loop ([kc][n][kk] coalesced). Swapped MFMA
// operands: lane = pix, regs = channels -> packed 8B scatter stores.
// ---------------------------------------------------------------------------
__global__ __launch_bounds__(256, 8) void vproj_mfma_kernel(
    const float* __restrict__ A,            // [VM][256] f32
    const unsigned short* __restrict__ wT,  // [kc][n][kk] bf16
    const float* __restrict__ bias,         // [256]
    unsigned short* __restrict__ v)         // [B][H][LV][32] bf16
{
    __shared__ __align__(16) unsigned short Asb[32 * 256];  // 16 KB, swizzled

    const int tid  = threadIdx.x;
    const int w    = tid >> 6;
    const int lane = tid & 63;
    const int mrow = lane & 15;
    const int quad = lane >> 4;
    const int m0   = blockIdx.x * 32;

    // ---- stage A tile (32 rows x 1KB), fully coalesced ----
#pragma unroll
    for (int r = 0; r < 8; ++r) {
        const int flat = r * 256 + tid;
        const int grow = flat >> 6;
        const int gcol = flat & 63;           // 16B f32 unit in the row
        int gm = m0 + grow; if (gm >= VM) gm = VM - 1;
        const float4 f = *(const float4*)(A + (size_t)gm * 256 + gcol * 4);
        uint2 pk;
        pk.x = pk2bf(f.x, f.y);
        pk.y = pk2bf(f.z, f.w);
        const int c  = gcol >> 1;
        const int cp = c ^ (grow & 31);
        *(uint2*)&Asb[grow * 256 + cp * 8 + (gcol & 1) * 4] = pk;
    }
    __syncthreads();

    f32x4 acc[2][4];
#pragma unroll
    for (int i = 0; i < 2; ++i)
#pragma unroll
        for (int j = 0; j < 4; ++j) acc[i][j] = (f32x4)0.f;

#pragma unroll
    for (int kc = 0; kc < 8; ++kc) {
        bf16x8 wfr[4], af[2];
#pragma unroll
        for (int j = 0; j < 4; ++j) {
            const int n = w * 64 + j * 16 + mrow;
            wfr[j] = *(const bf16x8*)(const void*)(wT + (((size_t)kc * 256 + n) << 5) + quad * 8);
        }
#pragma unroll
        for (int i = 0; i < 2; ++i) {
            const int mr = i * 16 + mrow;
            const int cp = (kc * 4 + quad) ^ (mr & 31);
            af[i] = *(const bf16x8*)(const void*)&Asb[mr * 256 + cp * 8];
        }
#pragma unroll
        for (int i = 0; i < 2; ++i)
#pragma unroll
            for (int j = 0; j < 4; ++j)
                acc[i][j] = __builtin_amdgcn_mfma_f32_16x16x32_bf16(
                    wfr[j], af[i], acc[i][j], 0, 0, 0);
    }

    float4 bj[4];
#pragma unroll
    for (int j = 0; j < 4; ++j)
        bj[j] = *(const float4*)(bias + w * 64 + j * 16 + quad * 4);

#pragma unroll
    for (int i = 0; i < 2; ++i) {
        const int gm = m0 + i * 16 + mrow;
        if (gm >= VM) continue;
        const unsigned int b   = (unsigned int)gm / (unsigned int)LV;
        const unsigned int pix = (unsigned int)gm - b * (unsigned int)LV;
#pragma unroll
        for (int j = 0; j < 4; ++j) {
            const int ch = w * 64 + j * 16 + quad * 4;
            const int h  = ch >> 5, cc = ch & 31;
            uint2 o;
            o.x = pk2bf(acc[i][j][0] + bj[j].x, acc[i][j][1] + bj[j].y);
            o.y = pk2bf(acc[i][j][2] + bj[j].z, acc[i][j][3] + bj[j].w);
            *(uint2*)(v + (((size_t)(b * NH + h)) * LV + pix) * HD + cc) = o;
        }
    }
}

// ---------------------------------------------------------------------------
// Generic coalesced MFMA GEMM, M-tile 16. C = A@W + bias, f32 out.
// A row-major [M][256] bf16 (+ optional lo part for split-precision),
// W [kc][n][kk] bf16, N = NJ*64 (4 waves x NJ*16 cols).
// ---------------------------------------------------------------------------
template<int NJ, bool SPLIT>
__global__ __launch_bounds__(256) void gemm16_kernel(
    const unsigned short* __restrict__ A,
    const unsigned short* __restrict__ A2,
    const unsigned short* __restrict__ wT,
    const float* __restrict__ bias,
    float* __restrict__ C)
{
    constexpr int N = NJ * 64;
    __shared__ __align__(16) unsigned short Ah[16 * 256];   // 8 KB
    __shared__ __align__(16) unsigned short Al[SPLIT ? 16 * 256 : 8];

    const int tid  = threadIdx.x;
    const int w    = tid >> 6;
    const int lane = tid & 63;
    const int mrow = lane & 15;
    const int quad = lane >> 4;
    const int m0   = blockIdx.x * 16;

    // stage A (and A2): 16 rows x 32 chunks = 512 chunks, 2 rounds
#pragma unroll
    for (int r = 0; r < 2; ++r) {
        const int flat = r * 256 + tid;
        const int row  = flat >> 5;
        const int ck   = flat & 31;
        const int cp   = ck ^ row;
        *(uint4*)&Ah[row * 256 + cp * 8] =
            *(const uint4*)(A + (size_t)(m0 + row) * 256 + ck * 8);
        if (SPLIT)
            *(uint4*)&Al[row * 256 + cp * 8] =
                *(const uint4*)(A2 + (size_t)(m0 + row) * 256 + ck * 8);
    }
    __syncthreads();

    f32x4 acc[NJ];
#pragma unroll
    for (int j = 0; j < NJ; ++j) acc[j] = (f32x4)0.f;

#pragma unroll
    for (int kc = 0; kc < 8; ++kc) {
        bf16x8 wf[NJ];
#pragma unroll
        for (int j = 0; j < NJ; ++j) {
            const int n = w * (NJ * 16) + j * 16 + mrow;
            wf[j] = *(const bf16x8*)(const void*)(wT + (((size_t)kc * N + n) << 5) + quad * 8);
        }
        const int cp = (kc * 4 + quad) ^ mrow;
        const bf16x8 af = *(const bf16x8*)(const void*)&Ah[mrow * 256 + cp * 8];
#pragma unroll
        for (int j = 0; j < NJ; ++j)
            acc[j] = __builtin_amdgcn_mfma_f32_16x16x32_bf16(wf[j], af, acc[j], 0, 0, 0);
        if (SPLIT) {
            const bf16x8 af2 = *(const bf16x8*)(const void*)&Al[mrow * 256 + cp * 8];
#pragma unroll
            for (int j = 0; j < NJ; ++j)
                acc[j] = __builtin_amdgcn_mfma_f32_16x16x32_bf16(wf[j], af2, acc[j], 0, 0, 0);
        }
    }

    const int gm = m0 + mrow;
#pragma unroll
    for (int j = 0; j < NJ; ++j) {
        const int col = w * (NJ * 16) + j * 16 + quad * 4;
        const float4 bb = *(const float4*)(bias + col);
        float4 o;
        o.x = acc[j][0] + bb.x;
        o.y = acc[j][1] + bb.y;
        o.z = acc[j][2] + bb.z;
        o.w = acc[j][3] + bb.w;
        *(float4*)(C + (size_t)gm * N + col) = o;
    }
}

// ---------------------------------------------------------------------------
// Sampling (validated R6/R7): one WAVE per (b,h,q). Lane = (pz, ch).
// ---------------------------------------------------------------------------
__global__ __launch_bounds__(256) void sample_kernel(
    const unsigned short* __restrict__ v,   // [B][H][LV][32] bf16
    const float* __restrict__ so_raw,       // [B*Q][256]
    const float* __restrict__ aw_raw,       // [B*Q][128] raw logits
    const float* __restrict__ refp,         // [B][Q][4][2]
    unsigned short* __restrict__ out_head)  // [B*Q][256] bf16
{
    const int blk = blockIdx.x;
    const int xcd = blk & 7;
    const int j   = blk >> 3;
    const int bh  = xcd * 8 + (j >> 8);
    const int qg  = j & 255;
    const int b   = bh >> 3;
    const int h   = bh & 7;

    const int wv   = threadIdx.x >> 6;
    const int lane = threadIdx.x & 63;
    const int ch   = lane & 7;
    const int pz   = lane >> 3;

    const int q  = qg * 4 + wv;
    const int rq = b * LQ + q;

    const float l0 = aw_raw[rq * 128 + h * 16 + pz];
    const float l1 = aw_raw[rq * 128 + h * 16 + 8 + pz];
    float mx = fmaxf(l0, l1);
    mx = fmaxf(mx, __shfl_xor(mx, 8));
    mx = fmaxf(mx, __shfl_xor(mx, 16));
    mx = fmaxf(mx, __shfl_xor(mx, 32));
    const float e0 = __expf(l0 - mx), e1 = __expf(l1 - mx);
    float sm = e0 + e1;
    sm += __shfl_xor(sm, 8);
    sm += __shfl_xor(sm, 16);
    sm += __shfl_xor(sm, 32);
    const float inv_s = 1.f / sm;

    const unsigned short* vb = v + (size_t)bh * (LV * HD) + ch * 4;

    float a0 = 0.f, a1 = 0.f, a2 = 0.f, a3 = 0.f;

#pragma unroll
    for (int r = 0; r < 2; ++r) {
        const int pt = r * 8 + pz;
        const int l  = pt >> 2;
        const int p  = pt & 3;
        const float wgt = (r ? e1 : e0) * inv_s;

        const int Wl = (l == 0) ? 100 : (l == 1) ? 50 : (l == 2) ? 25 : 13;
        const int st = (l == 0) ? 0 : (l == 1) ? 10000 : (l == 2) ? 12500 : 13125;
        const float invW = (l == 0) ? 0.01f : (l == 1) ? 0.02f : (l == 2) ? 0.04f
                                            : (1.0f / 13.0f);
        const float fw = (float)Wl;

        const float2 rxy = *(const float2*)(refp + (size_t)rq * 8 + l * 2);
        const float2 sxy = *(const float2*)(so_raw + (size_t)rq * 256 + h * 32 + l * 8 + p * 2);

        const float x = (rxy.x + sxy.x * invW) * fw - 0.5f;
        const float y = (rxy.y + sxy.y * invW) * fw - 0.5f;

        const float xf = floorf(x), yf = floorf(y);
        const int x0 = (int)xf, y0 = (int)yf;
        const float wx1 = x - xf, wx0 = 1.f - wx1;
        const float wy1 = y - yf, wy0 = 1.f - wy1;

        const float vx0 = (x0 >= 0 && x0 < Wl) ? 1.f : 0.f;
        const float vx1 = (x0 + 1 >= 0 && x0 + 1 < Wl) ? 1.f : 0.f;
        const float vy0 = (y0 >= 0 && y0 < Wl) ? 1.f : 0.f;
        const float vy1 = (y0 + 1 >= 0 && y0 + 1 < Wl) ? 1.f : 0.f;

        const int xc0 = min(max(x0, 0), Wl - 1);
        const int xc1 = min(max(x0 + 1, 0), Wl - 1);
        const int yc0 = min(max(y0, 0), Wl - 1);
        const int yc1 = min(max(y0 + 1, 0), Wl - 1);

        const float w00 = wgt * wy0 * wx0 * vy0 * vx0;
        const float w01 = wgt * wy0 * wx1 * vy0 * vx1;
        const float w10 = wgt * wy1 * wx0 * vy1 * vx0;
        const float w11 = wgt * wy1 * wx1 * vy1 * vx1;

        const int row0 = (st + yc0 * Wl) * HD;
        const int row1 = (st + yc1 * Wl) * HD;

        const ushort4 u00 = *(const ushort4*)(vb + row0 + xc0 * HD);
        const ushort4 u01 = *(const ushort4*)(vb + row0 + xc1 * HD);
        const ushort4 u10 = *(const ushort4*)(vb + row1 + xc0 * HD);
        const ushort4 u11 = *(const ushort4*)(vb + row1 + xc1 * HD);

        a0 = fmaf(w00, bf2f(u00.x), a0);
        a1 = fmaf(w00, bf2f(u00.y), a1);
        a2 = fmaf(w00, bf2f(u00.z), a2);
        a3 = fmaf(w00, bf2f(u00.w), a3);
        a0 = fmaf(w01, bf2f(u01.x), a0);
        a1 = fmaf(w01, bf2f(u01.y), a1);
        a2 = fmaf(w01, bf2f(u01.z), a2);
        a3 = fmaf(w01, bf2f(u01.w), a3);
        a0 = fmaf(w10, bf2f(u10.x), a0);
        a1 = fmaf(w10, bf2f(u10.y), a1);
        a2 = fmaf(w10, bf2f(u10.z), a2);
        a3 = fmaf(w10, bf2f(u10.w), a3);
        a0 = fmaf(w11, bf2f(u11.x), a0);
        a1 = fmaf(w11, bf2f(u11.y), a1);
        a2 = fmaf(w11, bf2f(u11.z), a2);
        a3 = fmaf(w11, bf2f(u11.w), a3);
    }

    a0 += __shfl_xor(a0, 8);  a1 += __shfl_xor(a1, 8);
    a2 += __shfl_xor(a2, 8);  a3 += __shfl_xor(a3, 8);
    a0 += __shfl_xor(a0, 16); a1 += __shfl_xor(a1, 16);
    a2 += __shfl_xor(a2, 16); a3 += __shfl_xor(a3, 16);
    a0 += __shfl_xor(a0, 32); a1 += __shfl_xor(a1, 32);
    a2 += __shfl_xor(a2, 32); a3 += __shfl_xor(a3, 32);

    if (pz == 0) {
        uint2 o;
        o.x = pk2bf(a0, a1);
        o.y = pk2bf(a2, a3);
        *(uint2*)(out_head + (size_t)rq * 256 + (h << 5) + (ch << 2)) = o;
    }
}

// ---------------------------------------------------------------------------
extern "C" void kernel_launch(void* const* d_in, const int* in_sizes, int n_in,
                              void* d_out, int out_size, void* d_ws, size_t ws_size,
                              hipStream_t stream)
{
    const float* query = (const float*)d_in[0];
    const float* refp  = (const float*)d_in[1];
    const float* value = (const float*)d_in[2];
    const float* so_w  = (const float*)d_in[4];
    const float* so_b  = (const float*)d_in[5];
    const float* aw_w  = (const float*)d_in[6];
    const float* aw_b  = (const float*)d_in[7];
    const float* vp_w  = (const float*)d_in[8];
    const float* vp_b  = (const float*)d_in[9];
    const float* op_w  = (const float*)d_in[10];
    const float* op_b  = (const float*)d_in[11];
    float* out = (float*)d_out;

    float* ws = (float*)d_ws;
    size_t off = 0;
    unsigned short* v = (unsigned short*)(ws + off);
    off += (size_t)BSZ * NH * LV * HD / 2;
    unsigned short* wTv  = (unsigned short*)(ws + off); off += 32768;
    unsigned short* wTo  = (unsigned short*)(ws + off); off += 32768;
    unsigned short* wTso = (unsigned short*)(ws + off); off += 32768;
    unsigned short* wTaw = (unsigned short*)(ws + off); off += 16384;
    unsigned short* qhi  = (unsigned short*)(ws + off); off += (size_t)MQ * 128;
    unsigned short* qlo  = (unsigned short*)(ws + off); off += (size_t)MQ * 128;
    float* so_raw = ws + off; off += (size_t)MQ * 256;
    float* aw_raw = ws + off; off += (size_t)MQ * 128;
    unsigned short* out_head = (unsigned short*)(ws + off);
    off += (size_t)MQ * 128;

    // 0) weight relayouts + query hi/lo split
    prep_kernel<<<2944, 256, 0, stream>>>(vp_w, op_w, so_w, aw_w, query,
                                          wTv, wTo, wTso, wTaw, qhi, qlo);

    // 1) value projection
    vproj_mfma_kernel<<<(VM + 31) / 32, 256, 0, stream>>>(value, wTv, vp_b, v);

    // 2) so / aw projections (split-precision bf16 MFMA)
    gemm16_kernel<4, true><<<MQ / 16, 256, 0, stream>>>(qhi, qlo, wTso, so_b, so_raw);
    gemm16_kernel<2, true><<<MQ / 16, 256, 0, stream>>>(qhi, qlo, wTaw, aw_b, aw_raw);

    // 3) deformable sampling -> out_head bf16
    sample_kernel<<<BSZ * NH * LQ / 4, 256, 0, stream>>>(
        v, so_raw, aw_raw, refp, out_head);

    // 4) output projection
    gemm16_kernel<4, false><<<MQ / 16, 256, 0, stream>>>(out_head, nullptr, wTo, op_b, out);
}

// Round 9
// 247.819 us; speedup vs baseline: 1.1750x; 1.1750x over previous
//
#include <hip/hip_runtime.h>
#include <hip/hip_bf16.h>
#include <math.h>

#define BSZ 8
#define LQ  1024
#define LV  13294
#define NH  8
#define HD  32
#define VM  (BSZ * LV)   // 106352 rows of value
#define MQ  (BSZ * LQ)   // 8192 query rows
#define NVB ((VM + 63) / 64)   // 1662 vproj blocks

typedef __attribute__((ext_vector_type(8))) short bf16x8;
typedef __attribute__((ext_vector_type(4))) float f32x4;

__device__ static inline unsigned short f2bf(float f) {
    unsigned int u = __float_as_uint(f);
    unsigned int r = (u + 0x7FFFu + ((u >> 16) & 1u)) >> 16;
    return (unsigned short)r;
}
__device__ static inline float bf2f(unsigned short s) {
    return __uint_as_float(((unsigned int)s) << 16);
}
__device__ static inline unsigned int pk2bf(float a, float b) {
    __hip_bfloat162 h = __float22bfloat162_rn(make_float2(a, b));
    return *(unsigned int*)&h;
}

// ---------------------------------------------------------------------------
// Prep: weight relayouts to [kc][n][kk] bf16 + query hi/lo split.
// ---------------------------------------------------------------------------
__global__ __launch_bounds__(256) void prep_kernel(
    const float* __restrict__ vp_w, const float* __restrict__ op_w,
    const float* __restrict__ so_w, const float* __restrict__ aw_w,
    const float* __restrict__ query,
    unsigned short* __restrict__ wTv, unsigned short* __restrict__ wTo,
    unsigned short* __restrict__ wTso, unsigned short* __restrict__ wTaw,
    unsigned short* __restrict__ qhi, unsigned short* __restrict__ qlo)
{
    const int blk = blockIdx.x;
    const int t   = threadIdx.x;
    if (blk < 768) {
        const int n = blk & 255;
        const int k = t;
        const float* w; unsigned short* o;
        if      (blk < 256) { w = vp_w; o = wTv; }
        else if (blk < 512) { w = op_w; o = wTo; }
        else                { w = so_w; o = wTso; }
        o[(((k >> 5) * 256 + n) << 5) + (k & 31)] = f2bf(w[k * 256 + n]);
    } else if (blk < 896) {
        const int n = blk - 768;
        const int k = t;
        wTaw[(((k >> 5) * 128 + n) << 5) + (k & 31)] = f2bf(aw_w[k * 128 + n]);
    } else {
        const int idx = (blk - 896) * 256 + t;
        const float4 f = *(const float4*)(query + (size_t)idx * 4);
        ushort4 hi, lo;
        hi.x = f2bf(f.x); lo.x = f2bf(f.x - bf2f(hi.x));
        hi.y = f2bf(f.y); lo.y = f2bf(f.y - bf2f(hi.y));
        hi.z = f2bf(f.z); lo.z = f2bf(f.z - bf2f(hi.z));
        hi.w = f2bf(f.w); lo.w = f2bf(f.w - bf2f(hi.w));
        *(ushort4*)(qhi + (size_t)idx * 4) = hi;
        *(ushort4*)(qlo + (size_t)idx * 4) = lo;
    }
}

// ---------------------------------------------------------------------------
// gemm16 body (M-tile 16): C = A@W (+A2@W) + bias, f32 out. lds: 16KB.
// ---------------------------------------------------------------------------
template<int NJ, bool SPLIT>
__device__ __forceinline__ void gemm16_body(
    unsigned short* __restrict__ lds,
    const unsigned short* __restrict__ A, const unsigned short* __restrict__ A2,
    const unsigned short* __restrict__ wT, const float* __restrict__ bias,
    float* __restrict__ C, int m0)
{
    constexpr int N = NJ * 64;
    unsigned short* Ah = lds;
    unsigned short* Al = lds + 16 * 256;

    const int tid  = threadIdx.x;
    const int w    = tid >> 6;
    const int lane = tid & 63;
    const int mrow = lane & 15;
    const int quad = lane >> 4;

#pragma unroll
    for (int r = 0; r < 2; ++r) {
        const int flat = r * 256 + tid;
        const int row  = flat >> 5;
        const int ck   = flat & 31;
        const int cp   = ck ^ row;
        *(uint4*)&Ah[row * 256 + cp * 8] =
            *(const uint4*)(A + (size_t)(m0 + row) * 256 + ck * 8);
        if (SPLIT)
            *(uint4*)&Al[row * 256 + cp * 8] =
                *(const uint4*)(A2 + (size_t)(m0 + row) * 256 + ck * 8);
    }
    __syncthreads();

    f32x4 acc[NJ];
#pragma unroll
    for (int j = 0; j < NJ; ++j) acc[j] = (f32x4)0.f;

#pragma unroll
    for (int kc = 0; kc < 8; ++kc) {
        bf16x8 wf[NJ];
#pragma unroll
        for (int j = 0; j < NJ; ++j) {
            const int n = w * (NJ * 16) + j * 16 + mrow;
            wf[j] = *(const bf16x8*)(const void*)(wT + (((size_t)kc * N + n) << 5) + quad * 8);
        }
        const int cp = (kc * 4 + quad) ^ mrow;
        const bf16x8 af = *(const bf16x8*)(const void*)&Ah[mrow * 256 + cp * 8];
#pragma unroll
        for (int j = 0; j < NJ; ++j)
            acc[j] = __builtin_amdgcn_mfma_f32_16x16x32_bf16(wf[j], af, acc[j], 0, 0, 0);
        if (SPLIT) {
            const bf16x8 af2 = *(const bf16x8*)(const void*)&Al[mrow * 256 + cp * 8];
#pragma unroll
            for (int j = 0; j < NJ; ++j)
                acc[j] = __builtin_amdgcn_mfma_f32_16x16x32_bf16(wf[j], af2, acc[j], 0, 0, 0);
        }
    }

    const int gm = m0 + mrow;
#pragma unroll
    for (int j = 0; j < NJ; ++j) {
        const int col = w * (NJ * 16) + j * 16 + quad * 4;
        const float4 bb = *(const float4*)(bias + col);
        float4 o;
        o.x = acc[j][0] + bb.x;
        o.y = acc[j][1] + bb.y;
        o.z = acc[j][2] + bb.z;
        o.w = acc[j][3] + bb.w;
        *(float4*)(C + (size_t)gm * N + col) = o;
    }
}

// ---------------------------------------------------------------------------
// Fused stage-1: blocks [0,NVB) vproj (R7-validated BM=64 body);
// [NVB, NVB+512) so-proj (NJ=4, split); [NVB+512, NVB+1024) aw-proj (NJ=2).
// ---------------------------------------------------------------------------
__global__ __launch_bounds__(256, 4) void fused1_kernel(
    const float* __restrict__ A,            // value [VM][256] f32
    const unsigned short* __restrict__ wTv, // [kc][n][kk]
    const float* __restrict__ vp_b,
    unsigned short* __restrict__ v,         // [B][H][LV][32] bf16
    const unsigned short* __restrict__ qhi,
    const unsigned short* __restrict__ qlo,
    const unsigned short* __restrict__ wTso, const float* __restrict__ so_b,
    float* __restrict__ so_raw,
    const unsigned short* __restrict__ wTaw, const float* __restrict__ aw_b,
    float* __restrict__ aw_raw)
{
    __shared__ __align__(16) unsigned short lds_u16[64 * 256];  // 32 KB

    const int blk = blockIdx.x;
    if (blk >= NVB) {
        if (blk < NVB + 512)
            gemm16_body<4, true>(lds_u16, qhi, qlo, wTso, so_b, so_raw,
                                 (blk - NVB) * 16);
        else
            gemm16_body<2, true>(lds_u16, qhi, qlo, wTaw, aw_b, aw_raw,
                                 (blk - NVB - 512) * 16);
        return;
    }

    // ---------------- vproj body (R7-validated) ----------------
    const int tid  = threadIdx.x;
    const int w    = tid >> 6;
    const int lane = tid & 63;
    const int mrow = lane & 15;
    const int quad = lane >> 4;
    const int m0   = blk * 64;

#pragma unroll
    for (int r = 0; r < 16; ++r) {
        const int flat = r * 256 + tid;
        const int grow = flat >> 6;
        const int gcol = flat & 63;
        int gm = m0 + grow; if (gm >= VM) gm = VM - 1;
        const float4 f = *(const float4*)(A + (size_t)gm * 256 + gcol * 4);
        uint2 pk;
        pk.x = pk2bf(f.x, f.y);
        pk.y = pk2bf(f.z, f.w);
        const int c  = gcol >> 1;
        const int cp = c ^ (grow & 31);
        *(uint2*)&lds_u16[grow * 256 + cp * 8 + (gcol & 1) * 4] = pk;
    }
    __syncthreads();

    f32x4 acc[4][4];
#pragma unroll
    for (int i = 0; i < 4; ++i)
#pragma unroll
        for (int j = 0; j < 4; ++j) acc[i][j] = (f32x4)0.f;

#pragma unroll
    for (int kc = 0; kc < 8; ++kc) {
        bf16x8 wfr[4], af[4];
#pragma unroll
        for (int j = 0; j < 4; ++j) {
            const int n = w * 64 + j * 16 + mrow;
            wfr[j] = *(const bf16x8*)(const void*)(wTv + (((size_t)kc * 256 + n) << 5) + quad * 8);
        }
#pragma unroll
        for (int i = 0; i < 4; ++i) {
            const int mr = i * 16 + mrow;
            const int cp = (kc * 4 + quad) ^ (mr & 31);
            af[i] = *(const bf16x8*)(const void*)&lds_u16[mr * 256 + cp * 8];
        }
#pragma unroll
        for (int i = 0; i < 4; ++i)
#pragma unroll
            for (int j = 0; j < 4; ++j)
                acc[i][j] = __builtin_amdgcn_mfma_f32_16x16x32_bf16(
                    wfr[j], af[i], acc[i][j], 0, 0, 0);
    }

    float4 bj[4];
#pragma unroll
    for (int j = 0; j < 4; ++j)
        bj[j] = *(const float4*)(vp_b + w * 64 + j * 16 + quad * 4);

#pragma unroll
    for (int i = 0; i < 4; ++i) {
        const int gm = m0 + i * 16 + mrow;
        if (gm >= VM) continue;
        const unsigned int b   = (unsigned int)gm / (unsigned int)LV;
        const unsigned int pix = (unsigned int)gm - b * (unsigned int)LV;
#pragma unroll
        for (int j = 0; j < 4; ++j) {
            const int ch = w * 64 + j * 16 + quad * 4;
            const int h  = ch >> 5, cc = ch & 31;
            uint2 o;
            o.x = pk2bf(acc[i][j][0] + bj[j].x, acc[i][j][1] + bj[j].y);
            o.y = pk2bf(acc[i][j][2] + bj[j].z, acc[i][j][3] + bj[j].w);
            *(uint2*)(v + (((size_t)(b * NH + h)) * LV + pix) * HD + cc) = o;
        }
    }
}

// ---------------------------------------------------------------------------
// Standalone oproj: d_out = out_head @ op_w + op_b.
// ---------------------------------------------------------------------------
__global__ __launch_bounds__(256) void oproj_kernel(
    const unsigned short* __restrict__ Ah,
    const unsigned short* __restrict__ wTo,
    const float* __restrict__ bias,
    float* __restrict__ C)
{
    __shared__ __align__(16) unsigned short lds_u16[16 * 256];
    gemm16_body<4, false>(lds_u16, Ah, nullptr, wTo, bias, C, blockIdx.x * 16);
}

// ---------------------------------------------------------------------------
// Sampling: one WAVE per (b,h,q). Lane = (pz: point-slot, ch: channel-group).
// Blocks grouped by (b,h) in PLAIN dispatch order (no XCD-mapping
// assumption): resident window spans few bh-slices -> L2/L3-hot gathers.
// ---------------------------------------------------------------------------
__global__ __launch_bounds__(256) void sample_kernel(
    const unsigned short* __restrict__ v,   // [B][H][LV][32] bf16
    const float* __restrict__ so_raw,       // [B*Q][256]
    const float* __restrict__ aw_raw,       // [B*Q][128] raw logits
    const float* __restrict__ refp,         // [B][Q][4][2]
    unsigned short* __restrict__ out_head)  // [B*Q][256] bf16
{
    const int blk = blockIdx.x;
    const int bh  = blk >> 8;              // 256 consecutive blocks per (b,h)
    const int j2  = blk & 255;
    const int b   = bh >> 3;
    const int h   = bh & 7;

    const int wv   = threadIdx.x >> 6;
    const int lane = threadIdx.x & 63;
    const int ch   = lane & 7;
    const int pz   = lane >> 3;

    const int q  = j2 * 4 + wv;
    const int rq = b * LQ + q;

    const float l0 = aw_raw[rq * 128 + h * 16 + pz];
    const float l1 = aw_raw[rq * 128 + h * 16 + 8 + pz];
    float mx = fmaxf(l0, l1);
    mx = fmaxf(mx, __shfl_xor(mx, 8));
    mx = fmaxf(mx, __shfl_xor(mx, 16));
    mx = fmaxf(mx, __shfl_xor(mx, 32));
    const float e0 = __expf(l0 - mx), e1 = __expf(l1 - mx);
    float sm = e0 + e1;
    sm += __shfl_xor(sm, 8);
    sm += __shfl_xor(sm, 16);
    sm += __shfl_xor(sm, 32);
    const float inv_s = 1.f / sm;

    const unsigned short* vb = v + (size_t)bh * (LV * HD) + ch * 4;

    float a0 = 0.f, a1 = 0.f, a2 = 0.f, a3 = 0.f;

#pragma unroll
    for (int r = 0; r < 2; ++r) {
        const int pt = r * 8 + pz;
        const int l  = pt >> 2;
        const int p  = pt & 3;
        const float wgt = (r ? e1 : e0) * inv_s;

        const int Wl = (l == 0) ? 100 : (l == 1) ? 50 : (l == 2) ? 25 : 13;
        const int st = (l == 0) ? 0 : (l == 1) ? 10000 : (l == 2) ? 12500 : 13125;
        const float invW = (l == 0) ? 0.01f : (l == 1) ? 0.02f : (l == 2) ? 0.04f
                                            : (1.0f / 13.0f);
        const float fw = (float)Wl;

        const float2 rxy = *(const float2*)(refp + (size_t)rq * 8 + l * 2);
        const float2 sxy = *(const float2*)(so_raw + (size_t)rq * 256 + h * 32 + l * 8 + p * 2);

        const float x = (rxy.x + sxy.x * invW) * fw - 0.5f;
        const float y = (rxy.y + sxy.y * invW) * fw - 0.5f;

        const float xf = floorf(x), yf = floorf(y);
        const int x0 = (int)xf, y0 = (int)yf;
        const float wx1 = x - xf, wx0 = 1.f - wx1;
        const float wy1 = y - yf, wy0 = 1.f - wy1;

        const float vx0 = (x0 >= 0 && x0 < Wl) ? 1.f : 0.f;
        const float vx1 = (x0 + 1 >= 0 && x0 + 1 < Wl) ? 1.f : 0.f;
        const float vy0 = (y0 >= 0 && y0 < Wl) ? 1.f : 0.f;
        const float vy1 = (y0 + 1 >= 0 && y0 + 1 < Wl) ? 1.f : 0.f;

        const int xc0 = min(max(x0, 0), Wl - 1);
        const int xc1 = min(max(x0 + 1, 0), Wl - 1);
        const int yc0 = min(max(y0, 0), Wl - 1);
        const int yc1 = min(max(y0 + 1, 0), Wl - 1);

        const float w00 = wgt * wy0 * wx0 * vy0 * vx0;
        const float w01 = wgt * wy0 * wx1 * vy0 * vx1;
        const float w10 = wgt * wy1 * wx0 * vy1 * vx0;
        const float w11 = wgt * wy1 * wx1 * vy1 * vx1;

        const int row0 = (st + yc0 * Wl) * HD;
        const int row1 = (st + yc1 * Wl) * HD;

        const ushort4 u00 = *(const ushort4*)(vb + row0 + xc0 * HD);
        const ushort4 u01 = *(const ushort4*)(vb + row0 + xc1 * HD);
        const ushort4 u10 = *(const ushort4*)(vb + row1 + xc0 * HD);
        const ushort4 u11 = *(const ushort4*)(vb + row1 + xc1 * HD);

        a0 = fmaf(w00, bf2f(u00.x), a0);
        a1 = fmaf(w00, bf2f(u00.y), a1);
        a2 = fmaf(w00, bf2f(u00.z), a2);
        a3 = fmaf(w00, bf2f(u00.w), a3);
        a0 = fmaf(w01, bf2f(u01.x), a0);
        a1 = fmaf(w01, bf2f(u01.y), a1);
        a2 = fmaf(w01, bf2f(u01.z), a2);
        a3 = fmaf(w01, bf2f(u01.w), a3);
        a0 = fmaf(w10, bf2f(u10.x), a0);
        a1 = fmaf(w10, bf2f(u10.y), a1);
        a2 = fmaf(w10, bf2f(u10.z), a2);
        a3 = fmaf(w10, bf2f(u10.w), a3);
        a0 = fmaf(w11, bf2f(u11.x), a0);
        a1 = fmaf(w11, bf2f(u11.y), a1);
        a2 = fmaf(w11, bf2f(u11.z), a2);
        a3 = fmaf(w11, bf2f(u11.w), a3);
    }

    a0 += __shfl_xor(a0, 8);  a1 += __shfl_xor(a1, 8);
    a2 += __shfl_xor(a2, 8);  a3 += __shfl_xor(a3, 8);
    a0 += __shfl_xor(a0, 16); a1 += __shfl_xor(a1, 16);
    a2 += __shfl_xor(a2, 16); a3 += __shfl_xor(a3, 16);
    a0 += __shfl_xor(a0, 32); a1 += __shfl_xor(a1, 32);
    a2 += __shfl_xor(a2, 32); a3 += __shfl_xor(a3, 32);

    if (pz == 0) {
        uint2 o;
        o.x = pk2bf(a0, a1);
        o.y = pk2bf(a2, a3);
        *(uint2*)(out_head + (size_t)rq * 256 + (h << 5) + (ch << 2)) = o;
    }
}

// ---------------------------------------------------------------------------
extern "C" void kernel_launch(void* const* d_in, const int* in_sizes, int n_in,
                              void* d_out, int out_size, void* d_ws, size_t ws_size,
                              hipStream_t stream)
{
    const float* query = (const float*)d_in[0];
    const float* refp  = (const float*)d_in[1];
    const float* value = (const float*)d_in[2];
    const float* so_w  = (const float*)d_in[4];
    const float* so_b  = (const float*)d_in[5];
    const float* aw_w  = (const float*)d_in[6];
    const float* aw_b  = (const float*)d_in[7];
    const float* vp_w  = (const float*)d_in[8];
    const float* vp_b  = (const float*)d_in[9];
    const float* op_w  = (const float*)d_in[10];
    const float* op_b  = (const float*)d_in[11];
    float* out = (float*)d_out;

    float* ws = (float*)d_ws;
    size_t off = 0;
    unsigned short* v = (unsigned short*)(ws + off);
    off += (size_t)BSZ * NH * LV * HD / 2;
    unsigned short* wTv  = (unsigned short*)(ws + off); off += 32768;
    unsigned short* wTo  = (unsigned short*)(ws + off); off += 32768;
    unsigned short* wTso = (unsigned short*)(ws + off); off += 32768;
    unsigned short* wTaw = (unsigned short*)(ws + off); off += 16384;
    unsigned short* qhi  = (unsigned short*)(ws + off); off += (size_t)MQ * 128;
    unsigned short* qlo  = (unsigned short*)(ws + off); off += (size_t)MQ * 128;
    float* so_raw = ws + off; off += (size_t)MQ * 256;
    float* aw_raw = ws + off; off += (size_t)MQ * 128;
    unsigned short* out_head = (unsigned short*)(ws + off);
    off += (size_t)MQ * 128;

    // 0) weight relayouts + query hi/lo split
    prep_kernel<<<2944, 256, 0, stream>>>(vp_w, op_w, so_w, aw_w, query,
                                          wTv, wTo, wTso, wTaw, qhi, qlo);

    // 1) fused vproj + so-proj + aw-proj
    fused1_kernel<<<NVB + 1024, 256, 0, stream>>>(
        value, wTv, vp_b, v, qhi, qlo, wTso, so_b, so_raw, wTaw, aw_b, aw_raw);

    // 2) deformable sampling -> out_head bf16
    sample_kernel<<<BSZ * NH * LQ / 4, 256, 0, stream>>>(
        v, so_raw, aw_raw, refp, out_head);

    // 3) output projection -> d_out
    oproj_kernel<<<MQ / 16, 256, 0, stream>>>(out_head, wTo, op_b, out);
}

// Round 10
// 247.164 us; speedup vs baseline: 1.1781x; 1.0026x over previous
//
#include <hip/hip_runtime.h>
#include <hip/hip_bf16.h>
#include <math.h>

#define BSZ 8
#define LQ  1024
#define LV  13294
#define NH  8
#define HD  32
#define VM  (BSZ * LV)   // 106352 rows of value
#define MQ  (BSZ * LQ)   // 8192 query rows
#define NVB ((VM + 63) / 64)   // 1662 vproj blocks

typedef __attribute__((ext_vector_type(8))) short bf16x8;
typedef __attribute__((ext_vector_type(4))) float f32x4;

__device__ static inline unsigned short f2bf(float f) {
    unsigned int u = __float_as_uint(f);
    unsigned int r = (u + 0x7FFFu + ((u >> 16) & 1u)) >> 16;
    return (unsigned short)r;
}
__device__ static inline float bf2f(unsigned short s) {
    return __uint_as_float(((unsigned int)s) << 16);
}
__device__ static inline unsigned int pk2bf(float a, float b) {
    __hip_bfloat162 h = __float22bfloat162_rn(make_float2(a, b));
    return *(unsigned int*)&h;
}

// ---------------------------------------------------------------------------
// Prep: weight relayouts to [kc][n][kk] bf16 only (query split is inlined
// into the so/aw staging now).
// ---------------------------------------------------------------------------
__global__ __launch_bounds__(256) void prep_kernel(
    const float* __restrict__ vp_w, const float* __restrict__ op_w,
    const float* __restrict__ so_w, const float* __restrict__ aw_w,
    unsigned short* __restrict__ wTv, unsigned short* __restrict__ wTo,
    unsigned short* __restrict__ wTso, unsigned short* __restrict__ wTaw)
{
    const int blk = blockIdx.x;
    const int t   = threadIdx.x;
    if (blk < 768) {
        const int n = blk & 255;
        const int k = t;
        const float* w; unsigned short* o;
        if      (blk < 256) { w = vp_w; o = wTv; }
        else if (blk < 512) { w = op_w; o = wTo; }
        else                { w = so_w; o = wTso; }
        o[(((k >> 5) * 256 + n) << 5) + (k & 31)] = f2bf(w[k * 256 + n]);
    } else {
        const int n = blk - 768;
        const int k = t;
        wTaw[(((k >> 5) * 128 + n) << 5) + (k & 31)] = f2bf(aw_w[k * 128 + n]);
    }
}

// ---------------------------------------------------------------------------
// gemm16 split body: C = split(Qf32)@W + bias. hi/lo computed during staging.
// lds usage: 16 KB.
// ---------------------------------------------------------------------------
template<int NJ>
__device__ __forceinline__ void gemm16_split_body(
    unsigned short* __restrict__ lds,
    const float* __restrict__ Q,
    const unsigned short* __restrict__ wT, const float* __restrict__ bias,
    float* __restrict__ C, int m0)
{
    constexpr int N = NJ * 64;
    unsigned short* Ah = lds;
    unsigned short* Al = lds + 16 * 256;

    const int tid  = threadIdx.x;
    const int w    = tid >> 6;
    const int lane = tid & 63;
    const int mrow = lane & 15;
    const int quad = lane >> 4;

#pragma unroll
    for (int r = 0; r < 2; ++r) {
        const int flat = r * 256 + tid;
        const int row  = flat >> 5;
        const int ck   = flat & 31;          // 8-elem chunk
        const float* qp = Q + (size_t)(m0 + row) * 256 + ck * 8;
        const float4 f0 = *(const float4*)qp;
        const float4 f1 = *(const float4*)(qp + 4);
        ushort4 h0, l0v;
        h0.x = f2bf(f0.x); l0v.x = f2bf(f0.x - bf2f(h0.x));
        h0.y = f2bf(f0.y); l0v.y = f2bf(f0.y - bf2f(h0.y));
        h0.z = f2bf(f0.z); l0v.z = f2bf(f0.z - bf2f(h0.z));
        h0.w = f2bf(f0.w); l0v.w = f2bf(f0.w - bf2f(h0.w));
        ushort4 h1, l1v;
        h1.x = f2bf(f1.x); l1v.x = f2bf(f1.x - bf2f(h1.x));
        h1.y = f2bf(f1.y); l1v.y = f2bf(f1.y - bf2f(h1.y));
        h1.z = f2bf(f1.z); l1v.z = f2bf(f1.z - bf2f(h1.z));
        h1.w = f2bf(f1.w); l1v.w = f2bf(f1.w - bf2f(h1.w));
        const int cp = ck ^ row;
        *(ushort4*)&Ah[row * 256 + cp * 8]     = h0;
        *(ushort4*)&Ah[row * 256 + cp * 8 + 4] = h1;
        *(ushort4*)&Al[row * 256 + cp * 8]     = l0v;
        *(ushort4*)&Al[row * 256 + cp * 8 + 4] = l1v;
    }
    __syncthreads();

    f32x4 acc[NJ];
#pragma unroll
    for (int j = 0; j < NJ; ++j) acc[j] = (f32x4)0.f;

#pragma unroll
    for (int kc = 0; kc < 8; ++kc) {
        bf16x8 wf[NJ];
#pragma unroll
        for (int j = 0; j < NJ; ++j) {
            const int n = w * (NJ * 16) + j * 16 + mrow;
            wf[j] = *(const bf16x8*)(const void*)(wT + (((size_t)kc * N + n) << 5) + quad * 8);
        }
        const int cp = (kc * 4 + quad) ^ mrow;
        const bf16x8 af  = *(const bf16x8*)(const void*)&Ah[mrow * 256 + cp * 8];
        const bf16x8 af2 = *(const bf16x8*)(const void*)&Al[mrow * 256 + cp * 8];
#pragma unroll
        for (int j = 0; j < NJ; ++j)
            acc[j] = __builtin_amdgcn_mfma_f32_16x16x32_bf16(wf[j], af, acc[j], 0, 0, 0);
#pragma unroll
        for (int j = 0; j < NJ; ++j)
            acc[j] = __builtin_amdgcn_mfma_f32_16x16x32_bf16(wf[j], af2, acc[j], 0, 0, 0);
    }

    const int gm = m0 + mrow;
#pragma unroll
    for (int j = 0; j < NJ; ++j) {
        const int col = w * (NJ * 16) + j * 16 + quad * 4;
        const float4 bb = *(const float4*)(bias + col);
        float4 o;
        o.x = acc[j][0] + bb.x;
        o.y = acc[j][1] + bb.y;
        o.z = acc[j][2] + bb.z;
        o.w = acc[j][3] + bb.w;
        *(float4*)(C + (size_t)gm * N + col) = o;
    }
}

// ---------------------------------------------------------------------------
// gemm16 bf16 body (oproj).
// ---------------------------------------------------------------------------
__device__ __forceinline__ void gemm16_bf16_body(
    unsigned short* __restrict__ lds,
    const unsigned short* __restrict__ A,
    const unsigned short* __restrict__ wT, const float* __restrict__ bias,
    float* __restrict__ C, int m0)
{
    unsigned short* Ah = lds;
    const int tid  = threadIdx.x;
    const int w    = tid >> 6;
    const int lane = tid & 63;
    const int mrow = lane & 15;
    const int quad = lane >> 4;

#pragma unroll
    for (int r = 0; r < 2; ++r) {
        const int flat = r * 256 + tid;
        const int row  = flat >> 5;
        const int ck   = flat & 31;
        const int cp   = ck ^ row;
        *(uint4*)&Ah[row * 256 + cp * 8] =
            *(const uint4*)(A + (size_t)(m0 + row) * 256 + ck * 8);
    }
    __syncthreads();

    f32x4 acc[4];
#pragma unroll
    for (int j = 0; j < 4; ++j) acc[j] = (f32x4)0.f;

#pragma unroll
    for (int kc = 0; kc < 8; ++kc) {
        bf16x8 wf[4];
#pragma unroll
        for (int j = 0; j < 4; ++j) {
            const int n = w * 64 + j * 16 + mrow;
            wf[j] = *(const bf16x8*)(const void*)(wT + (((size_t)kc * 256 + n) << 5) + quad * 8);
        }
        const int cp = (kc * 4 + quad) ^ mrow;
        const bf16x8 af = *(const bf16x8*)(const void*)&Ah[mrow * 256 + cp * 8];
#pragma unroll
        for (int j = 0; j < 4; ++j)
            acc[j] = __builtin_amdgcn_mfma_f32_16x16x32_bf16(wf[j], af, acc[j], 0, 0, 0);
    }

    const int gm = m0 + mrow;
#pragma unroll
    for (int j = 0; j < 4; ++j) {
        const int col = w * 64 + j * 16 + quad * 4;
        const float4 bb = *(const float4*)(bias + col);
        float4 o;
        o.x = acc[j][0] + bb.x;
        o.y = acc[j][1] + bb.y;
        o.z = acc[j][2] + bb.z;
        o.w = acc[j][3] + bb.w;
        *(float4*)(C + (size_t)gm * 256 + col) = o;
    }
}

// ---------------------------------------------------------------------------
// Fused stage-1: [0,NVB) vproj with explicit W-prefetch pipeline;
// [NVB,NVB+512) so-proj; [NVB+512,NVB+1024) aw-proj (inline q-split).
// ---------------------------------------------------------------------------
__global__ __launch_bounds__(256, 4) void fused1_kernel(
    const float* __restrict__ A,            // value [VM][256] f32
    const unsigned short* __restrict__ wTv, // [kc][n][kk]
    const float* __restrict__ vp_b,
    unsigned short* __restrict__ v,         // [B][H][LV][32] bf16
    const float* __restrict__ query,
    const unsigned short* __restrict__ wTso, const float* __restrict__ so_b,
    float* __restrict__ so_raw,
    const unsigned short* __restrict__ wTaw, const float* __restrict__ aw_b,
    float* __restrict__ aw_raw)
{
    __shared__ __align__(16) unsigned short lds_u16[64 * 256];  // 32 KB

    const int blk = blockIdx.x;
    if (blk >= NVB) {
        if (blk < NVB + 512)
            gemm16_split_body<4>(lds_u16, query, wTso, so_b, so_raw,
                                 (blk - NVB) * 16);
        else
            gemm16_split_body<2>(lds_u16, query, wTaw, aw_b, aw_raw,
                                 (blk - NVB - 512) * 16);
        return;
    }

    // ---------------- vproj body, W-prefetch pipelined ----------------
    const int tid  = threadIdx.x;
    const int w    = tid >> 6;
    const int lane = tid & 63;
    const int mrow = lane & 15;
    const int quad = lane >> 4;
    const int m0   = blk * 64;

#pragma unroll
    for (int r = 0; r < 16; ++r) {
        const int flat = r * 256 + tid;
        const int grow = flat >> 6;
        const int gcol = flat & 63;
        int gm = m0 + grow; if (gm >= VM) gm = VM - 1;
        const float4 f = *(const float4*)(A + (size_t)gm * 256 + gcol * 4);
        uint2 pk;
        pk.x = pk2bf(f.x, f.y);
        pk.y = pk2bf(f.z, f.w);
        const int c  = gcol >> 1;
        const int cp = c ^ (grow & 31);
        *(uint2*)&lds_u16[grow * 256 + cp * 8 + (gcol & 1) * 4] = pk;
    }
    __syncthreads();

    f32x4 acc[4][4];
#pragma unroll
    for (int i = 0; i < 4; ++i)
#pragma unroll
        for (int j = 0; j < 4; ++j) acc[i][j] = (f32x4)0.f;

#define LOADW(dst, kc_) {                                                     \
        _Pragma("unroll")                                                     \
        for (int j = 0; j < 4; ++j) {                                         \
            const int n = w * 64 + j * 16 + mrow;                             \
            dst[j] = *(const bf16x8*)(const void*)(wTv +                      \
                       (((size_t)(kc_) * 256 + n) << 5) + quad * 8);          \
        }                                                                     \
    }

    bf16x8 wcur[4], wnext[4];
    LOADW(wcur, 0);
    LOADW(wnext, 1);

#pragma unroll
    for (int kc = 0; kc < 8; ++kc) {
        bf16x8 af[4];
#pragma unroll
        for (int i = 0; i < 4; ++i) {
            const int mr = i * 16 + mrow;
            const int cp = (kc * 4 + quad) ^ (mr & 31);
            af[i] = *(const bf16x8*)(const void*)&lds_u16[mr * 256 + cp * 8];
        }
#pragma unroll
        for (int i = 0; i < 4; ++i)
#pragma unroll
            for (int j = 0; j < 4; ++j)
                acc[i][j] = __builtin_amdgcn_mfma_f32_16x16x32_bf16(
                    wcur[j], af[i], acc[i][j], 0, 0, 0);
        // rotate pipeline: consume next, prefetch kc+2
#pragma unroll
        for (int j = 0; j < 4; ++j) wcur[j] = wnext[j];
        if (kc < 6) LOADW(wnext, kc + 2);
    }
#undef LOADW

    float4 bj[4];
#pragma unroll
    for (int j = 0; j < 4; ++j)
        bj[j] = *(const float4*)(vp_b + w * 64 + j * 16 + quad * 4);

#pragma unroll
    for (int i = 0; i < 4; ++i) {
        const int gm = m0 + i * 16 + mrow;
        if (gm >= VM) continue;
        const unsigned int b   = (unsigned int)gm / (unsigned int)LV;
        const unsigned int pix = (unsigned int)gm - b * (unsigned int)LV;
#pragma unroll
        for (int j = 0; j < 4; ++j) {
            const int ch = w * 64 + j * 16 + quad * 4;
            const int h  = ch >> 5, cc = ch & 31;
            uint2 o;
            o.x = pk2bf(acc[i][j][0] + bj[j].x, acc[i][j][1] + bj[j].y);
            o.y = pk2bf(acc[i][j][2] + bj[j].z, acc[i][j][3] + bj[j].w);
            *(uint2*)(v + (((size_t)(b * NH + h)) * LV + pix) * HD + cc) = o;
        }
    }
}

// ---------------------------------------------------------------------------
// Standalone oproj.
// ---------------------------------------------------------------------------
__global__ __launch_bounds__(256) void oproj_kernel(
    const unsigned short* __restrict__ Ah,
    const unsigned short* __restrict__ wTo,
    const float* __restrict__ bias,
    float* __restrict__ C)
{
    __shared__ __align__(16) unsigned short lds_u16[16 * 256];
    gemm16_bf16_body(lds_u16, Ah, wTo, bias, C, blockIdx.x * 16);
}

// ---------------------------------------------------------------------------
// Sampling (R9-validated): one WAVE per (b,h,q), plain dispatch-order
// bh-grouping for L2 locality.
// ---------------------------------------------------------------------------
__global__ __launch_bounds__(256) void sample_kernel(
    const unsigned short* __restrict__ v,   // [B][H][LV][32] bf16
    const float* __restrict__ so_raw,       // [B*Q][256]
    const float* __restrict__ aw_raw,       // [B*Q][128] raw logits
    const float* __restrict__ refp,         // [B][Q][4][2]
    unsigned short* __restrict__ out_head)  // [B*Q][256] bf16
{
    const int blk = blockIdx.x;
    const int bh  = blk >> 8;
    const int j2  = blk & 255;
    const int b   = bh >> 3;
    const int h   = bh & 7;

    const int wv   = threadIdx.x >> 6;
    const int lane = threadIdx.x & 63;
    const int ch   = lane & 7;
    const int pz   = lane >> 3;

    const int q  = j2 * 4 + wv;
    const int rq = b * LQ + q;

    const float l0 = aw_raw[rq * 128 + h * 16 + pz];
    const float l1 = aw_raw[rq * 128 + h * 16 + 8 + pz];
    float mx = fmaxf(l0, l1);
    mx = fmaxf(mx, __shfl_xor(mx, 8));
    mx = fmaxf(mx, __shfl_xor(mx, 16));
    mx = fmaxf(mx, __shfl_xor(mx, 32));
    const float e0 = __expf(l0 - mx), e1 = __expf(l1 - mx);
    float sm = e0 + e1;
    sm += __shfl_xor(sm, 8);
    sm += __shfl_xor(sm, 16);
    sm += __shfl_xor(sm, 32);
    const float inv_s = 1.f / sm;

    const unsigned short* vb = v + (size_t)bh * (LV * HD) + ch * 4;

    float a0 = 0.f, a1 = 0.f, a2 = 0.f, a3 = 0.f;

#pragma unroll
    for (int r = 0; r < 2; ++r) {
        const int pt = r * 8 + pz;
        const int l  = pt >> 2;
        const int p  = pt & 3;
        const float wgt = (r ? e1 : e0) * inv_s;

        const int Wl = (l == 0) ? 100 : (l == 1) ? 50 : (l == 2) ? 25 : 13;
        const int st = (l == 0) ? 0 : (l == 1) ? 10000 : (l == 2) ? 12500 : 13125;
        const float invW = (l == 0) ? 0.01f : (l == 1) ? 0.02f : (l == 2) ? 0.04f
                                            : (1.0f / 13.0f);
        const float fw = (float)Wl;

        const float2 rxy = *(const float2*)(refp + (size_t)rq * 8 + l * 2);
        const float2 sxy = *(const float2*)(so_raw + (size_t)rq * 256 + h * 32 + l * 8 + p * 2);

        const float x = (rxy.x + sxy.x * invW) * fw - 0.5f;
        const float y = (rxy.y + sxy.y * invW) * fw - 0.5f;

        const float xf = floorf(x), yf = floorf(y);
        const int x0 = (int)xf, y0 = (int)yf;
        const float wx1 = x - xf, wx0 = 1.f - wx1;
        const float wy1 = y - yf, wy0 = 1.f - wy1;

        const float vx0 = (x0 >= 0 && x0 < Wl) ? 1.f : 0.f;
        const float vx1 = (x0 + 1 >= 0 && x0 + 1 < Wl) ? 1.f : 0.f;
        const float vy0 = (y0 >= 0 && y0 < Wl) ? 1.f : 0.f;
        const float vy1 = (y0 + 1 >= 0 && y0 + 1 < Wl) ? 1.f : 0.f;

        const int xc0 = min(max(x0, 0), Wl - 1);
        const int xc1 = min(max(x0 + 1, 0), Wl - 1);
        const int yc0 = min(max(y0, 0), Wl - 1);
        const int yc1 = min(max(y0 + 1, 0), Wl - 1);

        const float w00 = wgt * wy0 * wx0 * vy0 * vx0;
        const float w01 = wgt * wy0 * wx1 * vy0 * vx1;
        const float w10 = wgt * wy1 * wx0 * vy1 * vx0;
        const float w11 = wgt * wy1 * wx1 * vy1 * vx1;

        const int row0 = (st + yc0 * Wl) * HD;
        const int row1 = (st + yc1 * Wl) * HD;

        const ushort4 u00 = *(const ushort4*)(vb + row0 + xc0 * HD);
        const ushort4 u01 = *(const ushort4*)(vb + row0 + xc1 * HD);
        const ushort4 u10 = *(const ushort4*)(vb + row1 + xc0 * HD);
        const ushort4 u11 = *(const ushort4*)(vb + row1 + xc1 * HD);

        a0 = fmaf(w00, bf2f(u00.x), a0);
        a1 = fmaf(w00, bf2f(u00.y), a1);
        a2 = fmaf(w00, bf2f(u00.z), a2);
        a3 = fmaf(w00, bf2f(u00.w), a3);
        a0 = fmaf(w01, bf2f(u01.x), a0);
        a1 = fmaf(w01, bf2f(u01.y), a1);
        a2 = fmaf(w01, bf2f(u01.z), a2);
        a3 = fmaf(w01, bf2f(u01.w), a3);
        a0 = fmaf(w10, bf2f(u10.x), a0);
        a1 = fmaf(w10, bf2f(u10.y), a1);
        a2 = fmaf(w10, bf2f(u10.z), a2);
        a3 = fmaf(w10, bf2f(u10.w), a3);
        a0 = fmaf(w11, bf2f(u11.x), a0);
        a1 = fmaf(w11, bf2f(u11.y), a1);
        a2 = fmaf(w11, bf2f(u11.z), a2);
        a3 = fmaf(w11, bf2f(u11.w), a3);
    }

    a0 += __shfl_xor(a0, 8);  a1 += __shfl_xor(a1, 8);
    a2 += __shfl_xor(a2, 8);  a3 += __shfl_xor(a3, 8);
    a0 += __shfl_xor(a0, 16); a1 += __shfl_xor(a1, 16);
    a2 += __shfl_xor(a2, 16); a3 += __shfl_xor(a3, 16);
    a0 += __shfl_xor(a0, 32); a1 += __shfl_xor(a1, 32);
    a2 += __shfl_xor(a2, 32); a3 += __shfl_xor(a3, 32);

    if (pz == 0) {
        uint2 o;
        o.x = pk2bf(a0, a1);
        o.y = pk2bf(a2, a3);
        *(uint2*)(out_head + (size_t)rq * 256 + (h << 5) + (ch << 2)) = o;
    }
}

// ---------------------------------------------------------------------------
extern "C" void kernel_launch(void* const* d_in, const int* in_sizes, int n_in,
                              void* d_out, int out_size, void* d_ws, size_t ws_size,
                              hipStream_t stream)
{
    const float* query = (const float*)d_in[0];
    const float* refp  = (const float*)d_in[1];
    const float* value = (const float*)d_in[2];
    const float* so_w  = (const float*)d_in[4];
    const float* so_b  = (const float*)d_in[5];
    const float* aw_w  = (const float*)d_in[6];
    const float* aw_b  = (const float*)d_in[7];
    const float* vp_w  = (const float*)d_in[8];
    const float* vp_b  = (const float*)d_in[9];
    const float* op_w  = (const float*)d_in[10];
    const float* op_b  = (const float*)d_in[11];
    float* out = (float*)d_out;

    float* ws = (float*)d_ws;
    size_t off = 0;
    unsigned short* v = (unsigned short*)(ws + off);
    off += (size_t)BSZ * NH * LV * HD / 2;
    unsigned short* wTv  = (unsigned short*)(ws + off); off += 32768;
    unsigned short* wTo  = (unsigned short*)(ws + off); off += 32768;
    unsigned short* wTso = (unsigned short*)(ws + off); off += 32768;
    unsigned short* wTaw = (unsigned short*)(ws + off); off += 16384;
    float* so_raw = ws + off; off += (size_t)MQ * 256;
    float* aw_raw = ws + off; off += (size_t)MQ * 128;
    unsigned short* out_head = (unsigned short*)(ws + off);
    off += (size_t)MQ * 128;

    // 0) weight relayouts
    prep_kernel<<<896, 256, 0, stream>>>(vp_w, op_w, so_w, aw_w,
                                         wTv, wTo, wTso, wTaw);

    // 1) fused vproj (W-pipelined) + so-proj + aw-proj (inline q-split)
    fused1_kernel<<<NVB + 1024, 256, 0, stream>>>(
        value, wTv, vp_b, v, query, wTso, so_b, so_raw, wTaw, aw_b, aw_raw);

    // 2) deformable sampling -> out_head bf16
    sample_kernel<<<BSZ * NH * LQ / 4, 256, 0, stream>>>(
        v, so_raw, aw_raw, refp, out_head);

    // 3) output projection -> d_out
    oproj_kernel<<<MQ / 16, 256, 0, stream>>>(out_head, wTo, op_b, out);
}

// Round 12
// 247.087 us; speedup vs baseline: 1.1785x; 1.0003x over previous
//
#include <hip/hip_runtime.h>
#include <hip/hip_bf16.h>
#include <math.h>

#define BSZ 8
#define LQ  1024
#define LV  13294
#define NH  8
#define HD  32
#define VM  (BSZ * LV)   // 106352 rows of value
#define MQ  (BSZ * LQ)   // 8192 query rows
#define NVB ((VM + 63) / 64)   // 1662 vproj blocks

typedef __attribute__((ext_vector_type(8))) short bf16x8;
typedef __attribute__((ext_vector_type(4))) float f32x4;

__device__ static inline unsigned short f2bf(float f) {
    unsigned int u = __float_as_uint(f);
    unsigned int r = (u + 0x7FFFu + ((u >> 16) & 1u)) >> 16;
    return (unsigned short)r;
}
__device__ static inline float bf2f(unsigned short s) {
    return __uint_as_float(((unsigned int)s) << 16);
}
__device__ static inline unsigned int pk2bf(float a, float b) {
    __hip_bfloat162 h = __float22bfloat162_rn(make_float2(a, b));
    return *(unsigned int*)&h;
}

// ---------------------------------------------------------------------------
// Prep: weight relayouts to [kc][n][kk] bf16.
// ---------------------------------------------------------------------------
__global__ __launch_bounds__(256) void prep_kernel(
    const float* __restrict__ vp_w, const float* __restrict__ op_w,
    const float* __restrict__ so_w, const float* __restrict__ aw_w,
    unsigned short* __restrict__ wTv, unsigned short* __restrict__ wTo,
    unsigned short* __restrict__ wTso, unsigned short* __restrict__ wTaw)
{
    const int blk = blockIdx.x;
    const int t   = threadIdx.x;
    if (blk < 768) {
        const int n = blk & 255;
        const int k = t;
        const float* w; unsigned short* o;
        if      (blk < 256) { w = vp_w; o = wTv; }
        else if (blk < 512) { w = op_w; o = wTo; }
        else                { w = so_w; o = wTso; }
        o[(((k >> 5) * 256 + n) << 5) + (k & 31)] = f2bf(w[k * 256 + n]);
    } else {
        const int n = blk - 768;
        const int k = t;
        wTaw[(((k >> 5) * 128 + n) << 5) + (k & 31)] = f2bf(aw_w[k * 128 + n]);
    }
}

// ---------------------------------------------------------------------------
// gemm16 split body @512 threads: two 16-row tiles (half = w>>2), each with
// 4 waves covering N. C = split(Qf32)@W + bias.
// lds: per half 16 KB (Ah 8 KB + Al 8 KB) -> 32 KB total.
// ---------------------------------------------------------------------------
template<int NJ>
__device__ __forceinline__ void gemm16_split_body(
    unsigned short* __restrict__ lds,
    const float* __restrict__ Q,
    const unsigned short* __restrict__ wT, const float* __restrict__ bias,
    float* __restrict__ C, int m0_blk)
{
    constexpr int N = NJ * 64;
    const int tid  = threadIdx.x;
    const int w8   = tid >> 6;          // 0..7
    const int half = w8 >> 2;           // 0,1
    const int w    = w8 & 3;            // wave within half
    const int lane = tid & 63;
    const int mrow = lane & 15;
    const int quad = lane >> 4;
    const int m0   = m0_blk + half * 16;

    unsigned short* Ah = lds + half * 8192;
    unsigned short* Al = Ah + 16 * 256;

    // stage: threads of each half stage their own 16x256 tile (2 rounds)
    const int ht = tid & 255;
#pragma unroll
    for (int r = 0; r < 2; ++r) {
        const int flat = r * 256 + ht;
        const int row  = flat >> 5;          // 0..15
        const int ck   = flat & 31;
        const float* qp = Q + (size_t)(m0 + row) * 256 + ck * 8;
        const float4 f0 = *(const float4*)qp;
        const float4 f1 = *(const float4*)(qp + 4);
        ushort4 h0, l0v;
        h0.x = f2bf(f0.x); l0v.x = f2bf(f0.x - bf2f(h0.x));
        h0.y = f2bf(f0.y); l0v.y = f2bf(f0.y - bf2f(h0.y));
        h0.z = f2bf(f0.z); l0v.z = f2bf(f0.z - bf2f(h0.z));
        h0.w = f2bf(f0.w); l0v.w = f2bf(f0.w - bf2f(h0.w));
        ushort4 h1, l1v;
        h1.x = f2bf(f1.x); l1v.x = f2bf(f1.x - bf2f(h1.x));
        h1.y = f2bf(f1.y); l1v.y = f2bf(f1.y - bf2f(h1.y));
        h1.z = f2bf(f1.z); l1v.z = f2bf(f1.z - bf2f(h1.z));
        h1.w = f2bf(f1.w); l1v.w = f2bf(f1.w - bf2f(h1.w));
        const int cp = ck ^ row;             // row < 16, in range
        *(ushort4*)&Ah[row * 256 + cp * 8]     = h0;
        *(ushort4*)&Ah[row * 256 + cp * 8 + 4] = h1;
        *(ushort4*)&Al[row * 256 + cp * 8]     = l0v;
        *(ushort4*)&Al[row * 256 + cp * 8 + 4] = l1v;
    }
    __syncthreads();

    f32x4 acc[NJ];
#pragma unroll
    for (int j = 0; j < NJ; ++j) acc[j] = (f32x4)0.f;

#pragma unroll
    for (int kc = 0; kc < 8; ++kc) {
        bf16x8 wf[NJ];
#pragma unroll
        for (int j = 0; j < NJ; ++j) {
            const int n = w * (NJ * 16) + j * 16 + mrow;
            wf[j] = *(const bf16x8*)(const void*)(wT + (((size_t)kc * N + n) << 5) + quad * 8);
        }
        const int cp = (kc * 4 + quad) ^ mrow;
        const bf16x8 af  = *(const bf16x8*)(const void*)&Ah[mrow * 256 + cp * 8];
        const bf16x8 af2 = *(const bf16x8*)(const void*)&Al[mrow * 256 + cp * 8];
#pragma unroll
        for (int j = 0; j < NJ; ++j)
            acc[j] = __builtin_amdgcn_mfma_f32_16x16x32_bf16(wf[j], af, acc[j], 0, 0, 0);
#pragma unroll
        for (int j = 0; j < NJ; ++j)
            acc[j] = __builtin_amdgcn_mfma_f32_16x16x32_bf16(wf[j], af2, acc[j], 0, 0, 0);
    }

    const int gm = m0 + mrow;
#pragma unroll
    for (int j = 0; j < NJ; ++j) {
        const int col = w * (NJ * 16) + j * 16 + quad * 4;
        const float4 bb = *(const float4*)(bias + col);
        float4 o;
        o.x = acc[j][0] + bb.x;
        o.y = acc[j][1] + bb.y;
        o.z = acc[j][2] + bb.z;
        o.w = acc[j][3] + bb.w;
        *(float4*)(C + (size_t)gm * N + col) = o;
    }
}

// ---------------------------------------------------------------------------
// Fused stage-1 @512 threads:
//  [0, NVB): vproj, 8 waves x one head-slice (32 cols) each.
//  [NVB, NVB+256): so-proj (32 rows/block); [NVB+256, NVB+512): aw-proj.
// ---------------------------------------------------------------------------
__global__ __launch_bounds__(512, 4) void fused1_kernel(
    const float* __restrict__ A,            // value [VM][256] f32
    const unsigned short* __restrict__ wTv, // [kc][n][kk]
    const float* __restrict__ vp_b,
    unsigned short* __restrict__ v,         // [B][H][LV][32] bf16
    const float* __restrict__ query,
    const unsigned short* __restrict__ wTso, const float* __restrict__ so_b,
    float* __restrict__ so_raw,
    const unsigned short* __restrict__ wTaw, const float* __restrict__ aw_b,
    float* __restrict__ aw_raw)
{
    __shared__ __align__(16) unsigned short lds_u16[64 * 256];  // 32 KB

    const int blk = blockIdx.x;
    if (blk >= NVB) {
        if (blk < NVB + 256)
            gemm16_split_body<4>(lds_u16, query, wTso, so_b, so_raw,
                                 (blk - NVB) * 32);
        else
            gemm16_split_body<2>(lds_u16, query, wTaw, aw_b, aw_raw,
                                 (blk - NVB - 256) * 32);
        return;
    }

    // ---------------- vproj body: 8 waves, wave w = head w ----------------
    const int tid  = threadIdx.x;
    const int w    = tid >> 6;        // head
    const int lane = tid & 63;
    const int mrow = lane & 15;
    const int quad = lane >> 4;
    const int m0   = blk * 64;

    // stage A tile (64 rows x 1KB f32), coalesced: wave covers one row/instr
#pragma unroll
    for (int r = 0; r < 8; ++r) {
        const int flat = r * 512 + tid;
        const int grow = flat >> 6;
        const int gcol = flat & 63;
        int gm = m0 + grow; if (gm >= VM) gm = VM - 1;
        const float4 f = *(const float4*)(A + (size_t)gm * 256 + gcol * 4);
        uint2 pk;
        pk.x = pk2bf(f.x, f.y);
        pk.y = pk2bf(f.z, f.w);
        const int c  = gcol >> 1;
        const int cp = c ^ (grow & 31);
        *(uint2*)&lds_u16[grow * 256 + cp * 8 + (gcol & 1) * 4] = pk;
    }
    __syncthreads();

    f32x4 acc[4][2];
#pragma unroll
    for (int i = 0; i < 4; ++i)
#pragma unroll
        for (int j = 0; j < 2; ++j) acc[i][j] = (f32x4)0.f;

#pragma unroll
    for (int kc = 0; kc < 8; ++kc) {
        bf16x8 wfr[2], af[4];
#pragma unroll
        for (int j = 0; j < 2; ++j) {
            const int n = w * 32 + j * 16 + mrow;
            wfr[j] = *(const bf16x8*)(const void*)(wTv + (((size_t)kc * 256 + n) << 5) + quad * 8);
        }
#pragma unroll
        for (int i = 0; i < 4; ++i) {
            const int mr = i * 16 + mrow;
            const int cp = (kc * 4 + quad) ^ (mr & 31);
            af[i] = *(const bf16x8*)(const void*)&lds_u16[mr * 256 + cp * 8];
        }
#pragma unroll
        for (int i = 0; i < 4; ++i)
#pragma unroll
            for (int j = 0; j < 2; ++j)
                acc[i][j] = __builtin_amdgcn_mfma_f32_16x16x32_bf16(
                    wfr[j], af[i], acc[i][j], 0, 0, 0);
    }

    float4 bj[2];
#pragma unroll
    for (int j = 0; j < 2; ++j)
        bj[j] = *(const float4*)(vp_b + w * 32 + j * 16 + quad * 4);

#pragma unroll
    for (int i = 0; i < 4; ++i) {
        const int gm = m0 + i * 16 + mrow;
        if (gm >= VM) continue;
        const unsigned int b   = (unsigned int)gm / (unsigned int)LV;
        const unsigned int pix = (unsigned int)gm - b * (unsigned int)LV;
        unsigned short* vp = v + (((size_t)(b * NH + w)) * LV + pix) * HD;
#pragma unroll
        for (int j = 0; j < 2; ++j) {
            uint2 o;
            o.x = pk2bf(acc[i][j][0] + bj[j].x, acc[i][j][1] + bj[j].y);
            o.y = pk2bf(acc[i][j][2] + bj[j].z, acc[i][j][3] + bj[j].w);
            *(uint2*)(vp + j * 16 + quad * 4) = o;
        }
    }
}

// ---------------------------------------------------------------------------
// oproj @512 threads, BM=64: d_out = out_head(bf16) @ op_w + op_b, f32 out.
// FIX vs R11: staging swizzle masks the row (ck ^ (row & 31)) to stay inside
// the row's 32-chunk range — unmasked rows 32..63 corrupted LDS.
// ---------------------------------------------------------------------------
__global__ __launch_bounds__(512, 4) void oproj_kernel(
    const unsigned short* __restrict__ Ah,   // [8192][256] bf16
    const unsigned short* __restrict__ wTo,  // [kc][n][kk]
    const float* __restrict__ bias,
    float* __restrict__ out)                 // [8192][256] f32
{
    __shared__ __align__(16) unsigned short lds_u16[64 * 256];  // 32 KB

    const int tid  = threadIdx.x;
    const int w    = tid >> 6;
    const int lane = tid & 63;
    const int mrow = lane & 15;
    const int quad = lane >> 4;
    const int m0   = blockIdx.x * 64;

    // stage A (bf16, no convert): 64 rows x 512 B; 4 rounds x 16B/thread
#pragma unroll
    for (int r = 0; r < 4; ++r) {
        const int flat = r * 512 + tid;
        const int row  = flat >> 5;          // 0..63
        const int ck   = flat & 31;
        const int cp   = ck ^ (row & 31);    // FIXED: mask row
        *(uint4*)&lds_u16[row * 256 + cp * 8] =
            *(const uint4*)(Ah + (size_t)(m0 + row) * 256 + ck * 8);
    }
    __syncthreads();

    f32x4 acc[4][2];
#pragma unroll
    for (int i = 0; i < 4; ++i)
#pragma unroll
        for (int j = 0; j < 2; ++j) acc[i][j] = (f32x4)0.f;

#pragma unroll
    for (int kc = 0; kc < 8; ++kc) {
        bf16x8 wfr[2], af[4];
#pragma unroll
        for (int j = 0; j < 2; ++j) {
            const int n = w * 32 + j * 16 + mrow;
            wfr[j] = *(const bf16x8*)(const void*)(wTo + (((size_t)kc * 256 + n) << 5) + quad * 8);
        }
#pragma unroll
        for (int i = 0; i < 4; ++i) {
            const int mr = i * 16 + mrow;
            const int cp = (kc * 4 + quad) ^ (mr & 31);
            af[i] = *(const bf16x8*)(const void*)&lds_u16[mr * 256 + cp * 8];
        }
#pragma unroll
        for (int i = 0; i < 4; ++i)
#pragma unroll
            for (int j = 0; j < 2; ++j)
                acc[i][j] = __builtin_amdgcn_mfma_f32_16x16x32_bf16(
                    wfr[j], af[i], acc[i][j], 0, 0, 0);
    }

    float4 bj[2];
#pragma unroll
    for (int j = 0; j < 2; ++j)
        bj[j] = *(const float4*)(bias + w * 32 + j * 16 + quad * 4);

#pragma unroll
    for (int i = 0; i < 4; ++i) {
        const int gm = m0 + i * 16 + mrow;
#pragma unroll
        for (int j = 0; j < 2; ++j) {
            float4 o;
            o.x = acc[i][j][0] + bj[j].x;
            o.y = acc[i][j][1] + bj[j].y;
            o.z = acc[i][j][2] + bj[j].z;
            o.w = acc[i][j][3] + bj[j].w;
            *(float4*)(out + (size_t)gm * 256 + w * 32 + j * 16 + quad * 4) = o;
        }
    }
}

// ---------------------------------------------------------------------------
// Sampling (validated): one WAVE per (b,h,q), dispatch-order bh-grouping.
// ---------------------------------------------------------------------------
__global__ __launch_bounds__(256) void sample_kernel(
    const unsigned short* __restrict__ v,   // [B][H][LV][32] bf16
    const float* __restrict__ so_raw,       // [B*Q][256]
    const float* __restrict__ aw_raw,       // [B*Q][128] raw logits
    const float* __restrict__ refp,         // [B][Q][4][2]
    unsigned short* __restrict__ out_head)  // [B*Q][256] bf16
{
    const int blk = blockIdx.x;
    const int bh  = blk >> 8;
    const int j2  = blk & 255;
    const int b   = bh >> 3;
    const int h   = bh & 7;

    const int wv   = threadIdx.x >> 6;
    const int lane = threadIdx.x & 63;
    const int ch   = lane & 7;
    const int pz   = lane >> 3;

    const int q  = j2 * 4 + wv;
    const int rq = b * LQ + q;

    const float l0 = aw_raw[rq * 128 + h * 16 + pz];
    const float l1 = aw_raw[rq * 128 + h * 16 + 8 + pz];
    float mx = fmaxf(l0, l1);
    mx = fmaxf(mx, __shfl_xor(mx, 8));
    mx = fmaxf(mx, __shfl_xor(mx, 16));
    mx = fmaxf(mx, __shfl_xor(mx, 32));
    const float e0 = __expf(l0 - mx), e1 = __expf(l1 - mx);
    float sm = e0 + e1;
    sm += __shfl_xor(sm, 8);
    sm += __shfl_xor(sm, 16);
    sm += __shfl_xor(sm, 32);
    const float inv_s = 1.f / sm;

    const unsigned short* vb = v + (size_t)bh * (LV * HD) + ch * 4;

    float a0 = 0.f, a1 = 0.f, a2 = 0.f, a3 = 0.f;

#pragma unroll
    for (int r = 0; r < 2; ++r) {
        const int pt = r * 8 + pz;
        const int l  = pt >> 2;
        const int p  = pt & 3;
        const float wgt = (r ? e1 : e0) * inv_s;

        const int Wl = (l == 0) ? 100 : (l == 1) ? 50 : (l == 2) ? 25 : 13;
        const int st = (l == 0) ? 0 : (l == 1) ? 10000 : (l == 2) ? 12500 : 13125;
        const float invW = (l == 0) ? 0.01f : (l == 1) ? 0.02f : (l == 2) ? 0.04f
                                            : (1.0f / 13.0f);
        const float fw = (float)Wl;

        const float2 rxy = *(const float2*)(refp + (size_t)rq * 8 + l * 2);
        const float2 sxy = *(const float2*)(so_raw + (size_t)rq * 256 + h * 32 + l * 8 + p * 2);

        const float x = (rxy.x + sxy.x * invW) * fw - 0.5f;
        const float y = (rxy.y + sxy.y * invW) * fw - 0.5f;

        const float xf = floorf(x), yf = floorf(y);
        const int x0 = (int)xf, y0 = (int)yf;
        const float wx1 = x - xf, wx0 = 1.f - wx1;
        const float wy1 = y - yf, wy0 = 1.f - wy1;

        const float vx0 = (x0 >= 0 && x0 < Wl) ? 1.f : 0.f;
        const float vx1 = (x0 + 1 >= 0 && x0 + 1 < Wl) ? 1.f : 0.f;
        const float vy0 = (y0 >= 0 && y0 < Wl) ? 1.f : 0.f;
        const float vy1 = (y0 + 1 >= 0 && y0 + 1 < Wl) ? 1.f : 0.f;

        const int xc0 = min(max(x0, 0), Wl - 1);
        const int xc1 = min(max(x0 + 1, 0), Wl - 1);
        const int yc0 = min(max(y0, 0), Wl - 1);
        const int yc1 = min(max(y0 + 1, 0), Wl - 1);

        const float w00 = wgt * wy0 * wx0 * vy0 * vx0;
        const float w01 = wgt * wy0 * wx1 * vy0 * vx1;
        const float w10 = wgt * wy1 * wx0 * vy1 * vx0;
        const float w11 = wgt * wy1 * wx1 * vy1 * vx1;

        const int row0 = (st + yc0 * Wl) * HD;
        const int row1 = (st + yc1 * Wl) * HD;

        const ushort4 u00 = *(const ushort4*)(vb + row0 + xc0 * HD);
        const ushort4 u01 = *(const ushort4*)(vb + row0 + xc1 * HD);
        const ushort4 u10 = *(const ushort4*)(vb + row1 + xc0 * HD);
        const ushort4 u11 = *(const ushort4*)(vb + row1 + xc1 * HD);

        a0 = fmaf(w00, bf2f(u00.x), a0);
        a1 = fmaf(w00, bf2f(u00.y), a1);
        a2 = fmaf(w00, bf2f(u00.z), a2);
        a3 = fmaf(w00, bf2f(u00.w), a3);
        a0 = fmaf(w01, bf2f(u01.x), a0);
        a1 = fmaf(w01, bf2f(u01.y), a1);
        a2 = fmaf(w01, bf2f(u01.z), a2);
        a3 = fmaf(w01, bf2f(u01.w), a3);
        a0 = fmaf(w10, bf2f(u10.x), a0);
        a1 = fmaf(w10, bf2f(u10.y), a1);
        a2 = fmaf(w10, bf2f(u10.z), a2);
        a3 = fmaf(w10, bf2f(u10.w), a3);
        a0 = fmaf(w11, bf2f(u11.x), a0);
        a1 = fmaf(w11, bf2f(u11.y), a1);
        a2 = fmaf(w11, bf2f(u11.z), a2);
        a3 = fmaf(w11, bf2f(u11.w), a3);
    }

    a0 += __shfl_xor(a0, 8);  a1 += __shfl_xor(a1, 8);
    a2 += __shfl_xor(a2, 8);  a3 += __shfl_xor(a3, 8);
    a0 += __shfl_xor(a0, 16); a1 += __shfl_xor(a1, 16);
    a2 += __shfl_xor(a2, 16); a3 += __shfl_xor(a3, 16);
    a0 += __shfl_xor(a0, 32); a1 += __shfl_xor(a1, 32);
    a2 += __shfl_xor(a2, 32); a3 += __shfl_xor(a3, 32);

    if (pz == 0) {
        uint2 o;
        o.x = pk2bf(a0, a1);
        o.y = pk2bf(a2, a3);
        *(uint2*)(out_head + (size_t)rq * 256 + (h << 5) + (ch << 2)) = o;
    }
}

// ---------------------------------------------------------------------------
extern "C" void kernel_launch(void* const* d_in, const int* in_sizes, int n_in,
                              void* d_out, int out_size, void* d_ws, size_t ws_size,
                              hipStream_t stream)
{
    const float* query = (const float*)d_in[0];
    const float* refp  = (const float*)d_in[1];
    const float* value = (const float*)d_in[2];
    const float* so_w  = (const float*)d_in[4];
    const float* so_b  = (const float*)d_in[5];
    const float* aw_w  = (const float*)d_in[6];
    const float* aw_b  = (const float*)d_in[7];
    const float* vp_w  = (const float*)d_in[8];
    const float* vp_b  = (const float*)d_in[9];
    const float* op_w  = (const float*)d_in[10];
    const float* op_b  = (const float*)d_in[11];
    float* out = (float*)d_out;

    float* ws = (float*)d_ws;
    size_t off = 0;
    unsigned short* v = (unsigned short*)(ws + off);
    off += (size_t)BSZ * NH * LV * HD / 2;
    unsigned short* wTv  = (unsigned short*)(ws + off); off += 32768;
    unsigned short* wTo  = (unsigned short*)(ws + off); off += 32768;
    unsigned short* wTso = (unsigned short*)(ws + off); off += 32768;
    unsigned short* wTaw = (unsigned short*)(ws + off); off += 16384;
    float* so_raw = ws + off; off += (size_t)MQ * 256;
    float* aw_raw = ws + off; off += (size_t)MQ * 128;
    unsigned short* out_head = (unsigned short*)(ws + off);
    off += (size_t)MQ * 128;

    // 0) weight relayouts
    prep_kernel<<<896, 256, 0, stream>>>(vp_w, op_w, so_w, aw_w,
                                         wTv, wTo, wTso, wTaw);

    // 1) fused vproj (8-wave blocks) + so-proj + aw-proj
    fused1_kernel<<<NVB + 512, 512, 0, stream>>>(
        value, wTv, vp_b, v, query, wTso, so_b, so_raw, wTaw, aw_b, aw_raw);

    // 2) deformable sampling -> out_head bf16
    sample_kernel<<<BSZ * NH * LQ / 4, 256, 0, stream>>>(
        v, so_raw, aw_raw, refp, out_head);

    // 3) output projection -> d_out
    oproj_kernel<<<MQ / 64, 512, 0, stream>>>(out_head, wTo, op_b, out);
}